// Round 1
// baseline (558.438 us; speedup 1.0000x reference)
//
#include <hip/hip_runtime.h>
#include <hip/hip_bf16.h>
#include <cstdint>
#include <type_traits>

#define GLOBAL_AS __attribute__((address_space(1)))
#define LDS_AS    __attribute__((address_space(3)))

typedef short bf16x8 __attribute__((ext_vector_type(8)));
typedef short short8_t __attribute__((ext_vector_type(8)));
typedef float f32x4  __attribute__((ext_vector_type(4)));

static constexpr int E_DIM = 1024;   // hidden
static constexpr int N_HEADS = 16;
static constexpr int HD = 64;

__device__ __forceinline__ float b2f(short s) {
    union { unsigned u; float f; } x;
    x.u = ((unsigned)(unsigned short)s) << 16;
    return x.f;
}
__device__ __forceinline__ short f2b(float f) {
    union { float f; unsigned u; } x; x.f = f;
    unsigned r = x.u + 0x7FFF + ((x.u >> 16) & 1);
    return (short)(r >> 16);
}

// ---------------- fp32 -> bf16 convert, 4 elems/thread ----------------
__global__ __launch_bounds__(256) void k_convert(const float* __restrict__ in,
                                                 short* __restrict__ out, int n4) {
    int i = blockIdx.x * 256 + threadIdx.x;
    if (i >= n4) return;
    float4 v = reinterpret_cast<const float4*>(in)[i];
    short4 o;
    o.x = f2b(v.x); o.y = f2b(v.y); o.z = f2b(v.z); o.w = f2b(v.w);
    reinterpret_cast<short4*>(out)[i] = o;
}

// ---------------- bf16 GEMM: C[M][N] = A[M][K] * B[N][K]^T + bias ------
// m97 structure: 128x128 tile, BK=32, 4 waves (2x2), each wave 64x64 out.
template <typename OutT>
__global__ __launch_bounds__(256) void k_gemm_bias(
    const short* __restrict__ A,    // [M][K] bf16 bits
    const short* __restrict__ Bm,   // [N][K] bf16 bits (nn.Linear weight layout)
    const float* __restrict__ bias, // [N]
    OutT* __restrict__ C,           // [M][N]
    int M, int N, int K)
{
    __shared__ short As[128 * 32];
    __shared__ short Bs[128 * 32];

    const int tid  = threadIdx.x;
    const int lane = tid & 63;
    const int wv   = tid >> 6;
    const int wr   = wv >> 1, wc = wv & 1;
    const int m0   = blockIdx.x * 128;
    const int n0   = blockIdx.y * 128;

    const int frow = lane & 15;
    const int fk   = (lane >> 4) * 8;

    f32x4 acc[4][4];
    #pragma unroll
    for (int i = 0; i < 4; ++i)
        #pragma unroll
        for (int j = 0; j < 4; ++j)
            acc[i][j] = (f32x4){0.f, 0.f, 0.f, 0.f};

    // 16B staging chunks: chunk c -> tile row c>>2, k-offset (c&3)*8 elems
    const int c0 = tid, c1 = tid + 256;
    const int r0s = c0 >> 2, k0s = (c0 & 3) * 8;
    const int r1s = c1 >> 2, k1s = (c1 & 3) * 8;

    for (int kt = 0; kt < K; kt += 32) {
        __syncthreads();   // protect LDS from previous iteration's readers
        __builtin_amdgcn_global_load_lds((GLOBAL_AS void*)(A + (size_t)(m0 + r0s) * K + kt + k0s),
                                         (LDS_AS void*)(As + c0 * 8), 16, 0, 0);
        __builtin_amdgcn_global_load_lds((GLOBAL_AS void*)(A + (size_t)(m0 + r1s) * K + kt + k1s),
                                         (LDS_AS void*)(As + c1 * 8), 16, 0, 0);
        __builtin_amdgcn_global_load_lds((GLOBAL_AS void*)(Bm + (size_t)(n0 + r0s) * K + kt + k0s),
                                         (LDS_AS void*)(Bs + c0 * 8), 16, 0, 0);
        __builtin_amdgcn_global_load_lds((GLOBAL_AS void*)(Bm + (size_t)(n0 + r1s) * K + kt + k1s),
                                         (LDS_AS void*)(Bs + c1 * 8), 16, 0, 0);
        __syncthreads();   // staging complete (vmcnt(0) drained by barrier)

        bf16x8 af[4], bfv[4];
        #pragma unroll
        for (int mi = 0; mi < 4; ++mi)
            af[mi] = *reinterpret_cast<const bf16x8*>(&As[(wr * 64 + mi * 16 + frow) * 32 + fk]);
        #pragma unroll
        for (int ni = 0; ni < 4; ++ni)
            bfv[ni] = *reinterpret_cast<const bf16x8*>(&Bs[(wc * 64 + ni * 16 + frow) * 32 + fk]);
        #pragma unroll
        for (int mi = 0; mi < 4; ++mi)
            #pragma unroll
            for (int ni = 0; ni < 4; ++ni)
                acc[mi][ni] = __builtin_amdgcn_mfma_f32_16x16x32_bf16(af[mi], bfv[ni], acc[mi][ni], 0, 0, 0);
    }

    // epilogue: C/D layout col = lane&15, row = (lane>>4)*4 + r  (verified m89/m91)
    const int crow = (lane >> 4) * 4;
    const int ccol = lane & 15;
    #pragma unroll
    for (int ni = 0; ni < 4; ++ni) {
        const int col = n0 + wc * 64 + ni * 16 + ccol;
        const float bval = bias[col];
        #pragma unroll
        for (int mi = 0; mi < 4; ++mi) {
            const int r0 = m0 + wr * 64 + mi * 16 + crow;
            #pragma unroll
            for (int r = 0; r < 4; ++r) {
                float v = acc[mi][ni][r] + bval;
                if constexpr (std::is_same<OutT, float>::value) {
                    C[(size_t)(r0 + r) * N + col] = v;
                } else {
                    C[(size_t)(r0 + r) * N + col] = f2b(v);
                }
            }
        }
    }
}

// ---------------- per-token head-mixing attention ----------------------
// scores[h,g] = Q[tok,h,:].K[tok,g,:]/8 ; softmax over g ; out = P @ V
// one thread per (token, head); 16 tokens per 256-thread block; K/V in LDS.
__global__ __launch_bounds__(256) void k_attn(
    const short* __restrict__ Q, const short* __restrict__ K,
    const short* __restrict__ V, short* __restrict__ O)
{
    __shared__ short Ks[16][1032];   // +8 pad (16B) to rotate banks across tokens
    __shared__ short Vs[16][1032];

    const int tid = threadIdx.x;
    const int tok0 = blockIdx.x * 16;

    // stage K,V for 16 tokens (contiguous 32 KB each), coalesced 16B chunks
    for (int i = tid; i < 2048; i += 256) {
        int t = i >> 7;        // local token
        int j = i & 127;       // 16B chunk within token row
        *reinterpret_cast<short8_t*>(&Ks[t][j * 8]) =
            *reinterpret_cast<const short8_t*>(&K[(size_t)(tok0 + t) * E_DIM + j * 8]);
        *reinterpret_cast<short8_t*>(&Vs[t][j * 8]) =
            *reinterpret_cast<const short8_t*>(&V[(size_t)(tok0 + t) * E_DIM + j * 8]);
    }
    __syncthreads();

    const int tl = tid >> 4;     // local token
    const int h  = tid & 15;     // head

    // Q row -> fp32 regs
    float qf[64];
    const short* qp = Q + (size_t)(tok0 + tl) * E_DIM + h * HD;
    #pragma unroll
    for (int i = 0; i < 8; ++i) {
        short8_t v = *reinterpret_cast<const short8_t*>(&qp[i * 8]);
        #pragma unroll
        for (int j = 0; j < 8; ++j) qf[i * 8 + j] = b2f(v[j]);
    }

    // scores + softmax (16 values, in-register)
    float s[16];
    #pragma unroll
    for (int g = 0; g < 16; ++g) {
        float a = 0.f;
        #pragma unroll
        for (int i = 0; i < 8; ++i) {
            short8_t kv = *reinterpret_cast<const short8_t*>(&Ks[tl][g * HD + i * 8]);
            #pragma unroll
            for (int j = 0; j < 8; ++j) a += qf[i * 8 + j] * b2f(kv[j]);
        }
        s[g] = a * 0.125f;   // / sqrt(64)
    }
    float mx = s[0];
    #pragma unroll
    for (int g = 1; g < 16; ++g) mx = fmaxf(mx, s[g]);
    float l = 0.f;
    #pragma unroll
    for (int g = 0; g < 16; ++g) { s[g] = __expf(s[g] - mx); l += s[g]; }
    const float inv = 1.f / l;
    #pragma unroll
    for (int g = 0; g < 16; ++g) s[g] *= inv;

    // P @ V, 4 chunks of 16 outputs
    short* op = O + (size_t)(tok0 + tl) * E_DIM + h * HD;
    #pragma unroll
    for (int c = 0; c < 4; ++c) {
        float a[16];
        #pragma unroll
        for (int j = 0; j < 16; ++j) a[j] = 0.f;
        #pragma unroll
        for (int g = 0; g < 16; ++g) {
            short8_t v0 = *reinterpret_cast<const short8_t*>(&Vs[tl][g * HD + c * 16]);
            short8_t v1 = *reinterpret_cast<const short8_t*>(&Vs[tl][g * HD + c * 16 + 8]);
            #pragma unroll
            for (int j = 0; j < 8; ++j) {
                a[j]     += s[g] * b2f(v0[j]);
                a[8 + j] += s[g] * b2f(v1[j]);
            }
        }
        short8_t o0, o1;
        #pragma unroll
        for (int j = 0; j < 8; ++j) { o0[j] = f2b(a[j]); o1[j] = f2b(a[8 + j]); }
        *reinterpret_cast<short8_t*>(&op[c * 16])     = o0;
        *reinterpret_cast<short8_t*>(&op[c * 16 + 8]) = o1;
    }
}

extern "C" void kernel_launch(void* const* d_in, const int* in_sizes, int n_in,
                              void* d_out, int out_size, void* d_ws, size_t ws_size,
                              hipStream_t stream) {
    const float* x  = (const float*)d_in[0];
    const float* Wq = (const float*)d_in[1];
    const float* bq = (const float*)d_in[2];
    const float* Wk = (const float*)d_in[3];
    const float* bk = (const float*)d_in[4];
    const float* Wv = (const float*)d_in[5];
    const float* bv = (const float*)d_in[6];
    const float* Wo = (const float*)d_in[7];
    const float* bo = (const float*)d_in[8];
    float* out = (float*)d_out;

    const int T = in_sizes[0] / E_DIM;      // 32768 tokens
    char* ws = (char*)d_ws;
    const size_t SZ_X = (size_t)T * E_DIM * 2;        // 64 MiB
    const size_t SZ_W = (size_t)E_DIM * E_DIM * 2;    // 2 MiB

    short* xb  = (short*)(ws);
    short* Wqb = (short*)(ws + SZ_X);
    short* Wkb = (short*)(ws + SZ_X + 1 * SZ_W);
    short* Wvb = (short*)(ws + SZ_X + 2 * SZ_W);
    short* Wob = (short*)(ws + SZ_X + 3 * SZ_W);
    short* Qb  = (short*)(ws + SZ_X + 4 * SZ_W);
    short* Kb  = (short*)(ws + SZ_X + 4 * SZ_W + 1 * SZ_X);
    short* Vb  = (short*)(ws + SZ_X + 4 * SZ_W + 2 * SZ_X);
    short* Ab  = xb;   // reuse x-bf16 buffer for attention output

    const int n4x = T * E_DIM / 4;
    const int n4w = E_DIM * E_DIM / 4;
    k_convert<<<dim3((n4x + 255) / 256), dim3(256), 0, stream>>>(x,  xb,  n4x);
    k_convert<<<dim3((n4w + 255) / 256), dim3(256), 0, stream>>>(Wq, Wqb, n4w);
    k_convert<<<dim3((n4w + 255) / 256), dim3(256), 0, stream>>>(Wk, Wkb, n4w);
    k_convert<<<dim3((n4w + 255) / 256), dim3(256), 0, stream>>>(Wv, Wvb, n4w);
    k_convert<<<dim3((n4w + 255) / 256), dim3(256), 0, stream>>>(Wo, Wob, n4w);

    dim3 gg(T / 128, E_DIM / 128), gb(256);
    k_gemm_bias<short><<<gg, gb, 0, stream>>>(xb, Wqb, bq, Qb, T, E_DIM, E_DIM);
    k_gemm_bias<short><<<gg, gb, 0, stream>>>(xb, Wkb, bk, Kb, T, E_DIM, E_DIM);
    k_gemm_bias<short><<<gg, gb, 0, stream>>>(xb, Wvb, bv, Vb, T, E_DIM, E_DIM);

    k_attn<<<dim3(T / 16), dim3(256), 0, stream>>>(Qb, Kb, Vb, Ab);

    k_gemm_bias<float><<<gg, gb, 0, stream>>>(Ab, Wob, bo, out, T, E_DIM, E_DIM);
}

// Round 2
// 539.322 us; speedup vs baseline: 1.0354x; 1.0354x over previous
//
#include <hip/hip_runtime.h>
#include <hip/hip_bf16.h>
#include <cstdint>
#include <type_traits>

#define GLOBAL_AS __attribute__((address_space(1)))
#define LDS_AS    __attribute__((address_space(3)))

typedef short bf16x8 __attribute__((ext_vector_type(8)));
typedef short short8_t __attribute__((ext_vector_type(8)));
typedef float f32x4  __attribute__((ext_vector_type(4)));

static constexpr int E_DIM = 1024;   // hidden
static constexpr int N_HEADS = 16;
static constexpr int HD = 64;
static constexpr int QKV_STRIDE = 3072;

__device__ __forceinline__ float b2f(short s) {
    union { unsigned u; float f; } x;
    x.u = ((unsigned)(unsigned short)s) << 16;
    return x.f;
}
__device__ __forceinline__ short f2b(float f) {
    union { float f; unsigned u; } x; x.f = f;
    unsigned r = x.u + 0x7FFF + ((x.u >> 16) & 1);
    return (short)(r >> 16);
}

// ---------------- fp32 -> bf16 convert, 4 elems/thread ----------------
__global__ __launch_bounds__(256) void k_convert(const float* __restrict__ in,
                                                 short* __restrict__ out, int n4) {
    int i = blockIdx.x * 256 + threadIdx.x;
    if (i >= n4) return;
    float4 v = reinterpret_cast<const float4*>(in)[i];
    short4 o;
    o.x = f2b(v.x); o.y = f2b(v.y); o.z = f2b(v.z); o.w = f2b(v.w);
    reinterpret_cast<short4*>(out)[i] = o;
}

// ---------------- bias concat [bq | bk | bv] --------------------------
__global__ __launch_bounds__(256) void k_bcat(const float* __restrict__ bq,
                                              const float* __restrict__ bk,
                                              const float* __restrict__ bv,
                                              float* __restrict__ o) {
    int i = blockIdx.x * 256 + threadIdx.x;   // 3072 threads
    float v = (i < 1024) ? bq[i] : (i < 2048 ? bk[i - 1024] : bv[i - 2048]);
    o[i] = v;
}

// ---------------- bf16 GEMM: C[M][N] = A[M][K] * B[N][K]^T + bias ------
// m97 structure: 128x128 tile, BK=32, 4 waves (2x2), each wave 64x64 out.
// LDS k-slot XOR swizzle (rule #21): linear LDS dest for global_load_lds,
// pre-swizzled global SOURCE k-chunk, same XOR on the read side.
// slot' = slot ^ ((row>>1)&3) -> 8 consecutive rows cover all 32 banks.
template <typename OutT>
__global__ __launch_bounds__(256) void k_gemm_bias(
    const short* __restrict__ A,    // [M][K] bf16 bits
    const short* __restrict__ Bm,   // [N][K] bf16 bits (nn.Linear weight layout)
    const float* __restrict__ bias, // [N]
    OutT* __restrict__ C,           // [M][N]
    int M, int N, int K)
{
    __shared__ short As[128 * 32];
    __shared__ short Bs[128 * 32];

    const int tid  = threadIdx.x;
    const int lane = tid & 63;
    const int wv   = tid >> 6;
    const int wr   = wv >> 1, wc = wv & 1;
    const int m0   = blockIdx.x * 128;
    const int n0   = blockIdx.y * 128;

    const int frow = lane & 15;
    const int fks  = lane >> 4;                              // k-slot 0..3 wanted
    const int kswz = ((fks ^ ((frow >> 1) & 3)) * 8);        // swizzled k-offset (shorts)

    f32x4 acc[4][4];
    #pragma unroll
    for (int i = 0; i < 4; ++i)
        #pragma unroll
        for (int j = 0; j < 4; ++j)
            acc[i][j] = (f32x4){0.f, 0.f, 0.f, 0.f};

    // staging chunks: chunk c -> tile row c>>2, k-slot (c&3) ^ ((c>>3)&3)
    const int c0 = tid, c1 = tid + 256;
    const int r0s = c0 >> 2, q0s = (((c0 & 3) ^ ((c0 >> 3) & 3)) * 8);
    const int r1s = c1 >> 2, q1s = (((c1 & 3) ^ ((c1 >> 3) & 3)) * 8);

    for (int kt = 0; kt < K; kt += 32) {
        __syncthreads();   // protect LDS from previous iteration's readers
        __builtin_amdgcn_global_load_lds((GLOBAL_AS void*)(A + (size_t)(m0 + r0s) * K + kt + q0s),
                                         (LDS_AS void*)(As + c0 * 8), 16, 0, 0);
        __builtin_amdgcn_global_load_lds((GLOBAL_AS void*)(A + (size_t)(m0 + r1s) * K + kt + q1s),
                                         (LDS_AS void*)(As + c1 * 8), 16, 0, 0);
        __builtin_amdgcn_global_load_lds((GLOBAL_AS void*)(Bm + (size_t)(n0 + r0s) * K + kt + q0s),
                                         (LDS_AS void*)(Bs + c0 * 8), 16, 0, 0);
        __builtin_amdgcn_global_load_lds((GLOBAL_AS void*)(Bm + (size_t)(n0 + r1s) * K + kt + q1s),
                                         (LDS_AS void*)(Bs + c1 * 8), 16, 0, 0);
        __syncthreads();   // staging complete

        bf16x8 af[4], bfv[4];
        #pragma unroll
        for (int mi = 0; mi < 4; ++mi)
            af[mi] = *reinterpret_cast<const bf16x8*>(&As[(wr * 64 + mi * 16 + frow) * 32 + kswz]);
        #pragma unroll
        for (int ni = 0; ni < 4; ++ni)
            bfv[ni] = *reinterpret_cast<const bf16x8*>(&Bs[(wc * 64 + ni * 16 + frow) * 32 + kswz]);
        #pragma unroll
        for (int mi = 0; mi < 4; ++mi)
            #pragma unroll
            for (int ni = 0; ni < 4; ++ni)
                acc[mi][ni] = __builtin_amdgcn_mfma_f32_16x16x32_bf16(af[mi], bfv[ni], acc[mi][ni], 0, 0, 0);
    }

    // epilogue: C/D layout col = lane&15, row = (lane>>4)*4 + r (verified m89/m91)
    // loop order mi -> r -> ni so 4 consecutive stores cover 128B/row-quad (write-combine)
    const int crow = (lane >> 4) * 4;
    const int ccol = lane & 15;
    float bv4[4];
    #pragma unroll
    for (int ni = 0; ni < 4; ++ni)
        bv4[ni] = bias[n0 + wc * 64 + ni * 16 + ccol];
    #pragma unroll
    for (int mi = 0; mi < 4; ++mi) {
        #pragma unroll
        for (int r = 0; r < 4; ++r) {
            const size_t rowg = (size_t)(m0 + wr * 64 + mi * 16 + crow + r) * N;
            #pragma unroll
            for (int ni = 0; ni < 4; ++ni) {
                const int col = n0 + wc * 64 + ni * 16 + ccol;
                float v = acc[mi][ni][r] + bv4[ni];
                if constexpr (std::is_same<OutT, float>::value) {
                    C[rowg + col] = v;
                } else {
                    C[rowg + col] = f2b(v);
                }
            }
        }
    }
}

// ---------------- per-token head-mixing attention ----------------------
// QKV fused layout: row t = [q(1024) | k(1024) | v(1024)], stride 3072.
// scores[h,g] = Q[t,h,:].K[t,g,:]/8 ; softmax over g ; out = P @ V
__global__ __launch_bounds__(256) void k_attn(
    const short* __restrict__ QKV, short* __restrict__ O)
{
    __shared__ short Ks[16][1032];   // +8 pad to rotate banks across tokens
    __shared__ short Vs[16][1032];

    const int tid = threadIdx.x;
    const int tok0 = blockIdx.x * 16;

    // stage K,V for 16 tokens, coalesced 16B chunks
    for (int i = tid; i < 2048; i += 256) {
        int t = i >> 7;        // local token
        int j = i & 127;       // 16B chunk within 1024-elem row
        const size_t base = (size_t)(tok0 + t) * QKV_STRIDE;
        *reinterpret_cast<short8_t*>(&Ks[t][j * 8]) =
            *reinterpret_cast<const short8_t*>(&QKV[base + 1024 + j * 8]);
        *reinterpret_cast<short8_t*>(&Vs[t][j * 8]) =
            *reinterpret_cast<const short8_t*>(&QKV[base + 2048 + j * 8]);
    }
    __syncthreads();

    const int tl = tid >> 4;     // local token
    const int h  = tid & 15;     // head

    // Q row -> fp32 regs
    float qf[64];
    const short* qp = QKV + (size_t)(tok0 + tl) * QKV_STRIDE + h * HD;
    #pragma unroll
    for (int i = 0; i < 8; ++i) {
        short8_t v = *reinterpret_cast<const short8_t*>(&qp[i * 8]);
        #pragma unroll
        for (int j = 0; j < 8; ++j) qf[i * 8 + j] = b2f(v[j]);
    }

    // scores + softmax (16 values, in-register)
    float s[16];
    #pragma unroll
    for (int g = 0; g < 16; ++g) {
        float a = 0.f;
        #pragma unroll
        for (int i = 0; i < 8; ++i) {
            short8_t kv = *reinterpret_cast<const short8_t*>(&Ks[tl][g * HD + i * 8]);
            #pragma unroll
            for (int j = 0; j < 8; ++j) a += qf[i * 8 + j] * b2f(kv[j]);
        }
        s[g] = a * 0.125f;   // / sqrt(64)
    }
    float mx = s[0];
    #pragma unroll
    for (int g = 1; g < 16; ++g) mx = fmaxf(mx, s[g]);
    float l = 0.f;
    #pragma unroll
    for (int g = 0; g < 16; ++g) { s[g] = __expf(s[g] - mx); l += s[g]; }
    const float inv = 1.f / l;
    #pragma unroll
    for (int g = 0; g < 16; ++g) s[g] *= inv;

    // P @ V, 4 chunks of 16 outputs
    short* op = O + (size_t)(tok0 + tl) * E_DIM + h * HD;
    #pragma unroll
    for (int c = 0; c < 4; ++c) {
        float a[16];
        #pragma unroll
        for (int j = 0; j < 16; ++j) a[j] = 0.f;
        #pragma unroll
        for (int g = 0; g < 16; ++g) {
            short8_t v0 = *reinterpret_cast<const short8_t*>(&Vs[tl][g * HD + c * 16]);
            short8_t v1 = *reinterpret_cast<const short8_t*>(&Vs[tl][g * HD + c * 16 + 8]);
            #pragma unroll
            for (int j = 0; j < 8; ++j) {
                a[j]     += s[g] * b2f(v0[j]);
                a[8 + j] += s[g] * b2f(v1[j]);
            }
        }
        short8_t o0, o1;
        #pragma unroll
        for (int j = 0; j < 8; ++j) { o0[j] = f2b(a[j]); o1[j] = f2b(a[8 + j]); }
        *reinterpret_cast<short8_t*>(&op[c * 16])     = o0;
        *reinterpret_cast<short8_t*>(&op[c * 16 + 8]) = o1;
    }
}

extern "C" void kernel_launch(void* const* d_in, const int* in_sizes, int n_in,
                              void* d_out, int out_size, void* d_ws, size_t ws_size,
                              hipStream_t stream) {
    const float* x  = (const float*)d_in[0];
    const float* Wq = (const float*)d_in[1];
    const float* bq = (const float*)d_in[2];
    const float* Wk = (const float*)d_in[3];
    const float* bk = (const float*)d_in[4];
    const float* Wv = (const float*)d_in[5];
    const float* bv = (const float*)d_in[6];
    const float* Wo = (const float*)d_in[7];
    const float* bo = (const float*)d_in[8];
    float* out = (float*)d_out;

    const int T = in_sizes[0] / E_DIM;      // 32768 tokens
    char* ws = (char*)d_ws;
    const size_t SZ_X    = (size_t)T * E_DIM * 2;          // 64 MiB
    const size_t SZ_WQKV = (size_t)3 * E_DIM * E_DIM * 2;  // 6 MiB
    const size_t SZ_W    = (size_t)E_DIM * E_DIM * 2;      // 2 MiB
    const size_t SZ_B    = 3072 * sizeof(float) + 4096;    // bias concat (padded)

    short* xb    = (short*)(ws);
    short* Wqkvb = (short*)(ws + SZ_X);
    short* Wob   = (short*)(ws + SZ_X + SZ_WQKV);
    float* bqkv  = (float*)(ws + SZ_X + SZ_WQKV + SZ_W);
    short* QKVb  = (short*)(ws + SZ_X + SZ_WQKV + SZ_W + SZ_B);
    short* Ab    = xb;   // reuse x-bf16 buffer for attention output

    const int n4x = T * E_DIM / 4;
    const int n4w = E_DIM * E_DIM / 4;
    k_convert<<<dim3((n4x + 255) / 256), dim3(256), 0, stream>>>(x,  xb, n4x);
    k_convert<<<dim3((n4w + 255) / 256), dim3(256), 0, stream>>>(Wq, Wqkvb,                   n4w);
    k_convert<<<dim3((n4w + 255) / 256), dim3(256), 0, stream>>>(Wk, Wqkvb + E_DIM * E_DIM,     n4w);
    k_convert<<<dim3((n4w + 255) / 256), dim3(256), 0, stream>>>(Wv, Wqkvb + 2 * E_DIM * E_DIM, n4w);
    k_convert<<<dim3((n4w + 255) / 256), dim3(256), 0, stream>>>(Wo, Wob, n4w);
    k_bcat<<<dim3(12), dim3(256), 0, stream>>>(bq, bk, bv, bqkv);

    // fused QKV GEMM: [T][3072] = xb[T][1024] @ Wqkv[3072][1024]^T + bqkv
    k_gemm_bias<short><<<dim3(T / 128, QKV_STRIDE / 128), dim3(256), 0, stream>>>(
        xb, Wqkvb, bqkv, QKVb, T, QKV_STRIDE, E_DIM);

    k_attn<<<dim3(T / 16), dim3(256), 0, stream>>>(QKVb, Ab);

    k_gemm_bias<float><<<dim3(T / 128, E_DIM / 128), dim3(256), 0, stream>>>(
        Ab, Wob, bo, out, T, E_DIM, E_DIM);
}

// Round 4
// 424.762 us; speedup vs baseline: 1.3147x; 1.2697x over previous
//
#include <hip/hip_runtime.h>
#include <hip/hip_bf16.h>
#include <cstdint>
#include <type_traits>

#define GLOBAL_AS __attribute__((address_space(1)))
#define LDS_AS    __attribute__((address_space(3)))

typedef short bf16x8 __attribute__((ext_vector_type(8)));
typedef short short8_t __attribute__((ext_vector_type(8)));
typedef float f32x4  __attribute__((ext_vector_type(4)));

static constexpr int E_DIM = 1024;   // hidden
static constexpr int HD = 64;
static constexpr int QKV_STRIDE = 3072;
static constexpr int KDIM = 1024;        // K for both GEMMs
static constexpr int NT_K = KDIM / 64;   // 16 K-tiles
static constexpr int NIT  = NT_K / 2;    // 8 iterations (2 K-tiles each)

__device__ __forceinline__ float b2f(short s) {
    union { unsigned u; float f; } x;
    x.u = ((unsigned)(unsigned short)s) << 16;
    return x.f;
}
__device__ __forceinline__ short f2b(float f) {
    union { float f; unsigned u; } x; x.f = f;
    unsigned r = x.u + 0x7FFF + ((x.u >> 16) & 1);
    return (short)(r >> 16);
}

// ---------------- fp32 -> bf16 convert ----------------
__global__ __launch_bounds__(256) void k_convert(const float* __restrict__ in,
                                                 short* __restrict__ out, int n4) {
    int i = blockIdx.x * 256 + threadIdx.x;
    if (i >= n4) return;
    float4 v = reinterpret_cast<const float4*>(in)[i];
    short4 o;
    o.x = f2b(v.x); o.y = f2b(v.y); o.z = f2b(v.z); o.w = f2b(v.w);
    reinterpret_cast<short4*>(out)[i] = o;
}

// ---------------- bias concat [bq | bk | bv] ----------
__global__ __launch_bounds__(256) void k_bcat(const float* __restrict__ bq,
                                              const float* __restrict__ bk,
                                              const float* __restrict__ bv,
                                              float* __restrict__ o) {
    int i = blockIdx.x * 256 + threadIdx.x;
    float v = (i < 1024) ? bq[i] : (i < 2048 ? bk[i - 1024] : bv[i - 2048]);
    o[i] = v;
}

// ============ 256x256 8-phase bf16 GEMM (T2+T3+T4+T5 template) ============
// C[M][N] = A[M][K] * B[N][K]^T + bias. K = KDIM = 1024 fixed.
// 512 threads = 8 waves (2M x 4N), per-wave 128x64 output.
// LDS: 2 buffers x {A,B} x 2 k-halves x 16 KiB = 128 KiB.
// Sync protocol (derived, FIFO-counted; 2 loads/STAGE/wave):
//   vmcnt(8) at END of even phases (queue=12 there -> retires the 2 STAGEs
//   consumed right after this phase's trailing barrier). Wait ALWAYS precedes
//   a barrier that precedes the consuming ds_read -> cross-wave safe.
template <typename OutT>
__global__ __launch_bounds__(512, 2) void k_gemm256(
    const short* __restrict__ A,    // [M][KDIM]
    const short* __restrict__ Bm,   // [N][KDIM]
    const float* __restrict__ bias, // [N]
    OutT* __restrict__ C,           // [M][N]
    int NT_N, int N)
{
    __shared__ short lds[2][2][2][8192];   // [buf][A=0/B=1][khalf][16 KiB]

    const int tid  = threadIdx.x;
    const int lane = tid & 63;
    const int wv   = tid >> 6;      // 0..7
    const int wr   = wv >> 2;       // 0..1  (M half)
    const int wc   = wv & 3;        // 0..3  (N quarter)
    const int frow = lane & 15;
    const int ks   = lane >> 4;     // k-slot 0..3 within k-half

    // bijective XCD swizzle (grid % 8 == 0), n-fastest so neighbors share A-panel
    const int nwg  = gridDim.x;
    const int nper = nwg >> 3;
    const int bid  = blockIdx.x;
    const int swz  = (bid & 7) * nper + (bid >> 3);
    const int m0   = (swz / NT_N) * 256;
    const int n0   = (swz % NT_N) * 256;

    // staging: chunk c -> (row = c>>2, slot = (c&3)^((c>>3)&3)); linear LDS dest,
    // pre-swizzled global source (rule #21)
    const int c0 = tid, c1 = tid + 512;
    const int r0 = c0 >> 2, z0 = ((c0 & 3) ^ ((c0 >> 3) & 3)) * 8;
    const int r1 = c1 >> 2, z1 = ((c1 & 3) ^ ((c1 >> 3) & 3)) * 8;

#define STAGE(BUF, MAT, KH, BASE, ROW0, KT) do {                                   \
    __builtin_amdgcn_global_load_lds(                                              \
        (const GLOBAL_AS short*)((BASE) + (size_t)((ROW0) + r0) * KDIM +           \
                                 (KT) * 64 + (KH) * 32 + z0),                      \
        (LDS_AS short*)&lds[BUF][MAT][KH][c0 * 8], 16, 0, 0);                      \
    __builtin_amdgcn_global_load_lds(                                              \
        (const GLOBAL_AS short*)((BASE) + (size_t)((ROW0) + r1) * KDIM +           \
                                 (KT) * 64 + (KH) * 32 + z1),                      \
        (LDS_AS short*)&lds[BUF][MAT][KH][c1 * 8], 16, 0, 0);                      \
} while (0)

#define LDA(BUF, KH, R) (*reinterpret_cast<const bf16x8*>(                         \
        &lds[BUF][0][KH][((R) * 4 + (ks ^ (((R) >> 1) & 3))) * 8]))
#define LDB(BUF, KH, R) (*reinterpret_cast<const bf16x8*>(                         \
        &lds[BUF][1][KH][((R) * 4 + (ks ^ (((R) >> 1) & 3))) * 8]))

    f32x4 acc[8][4];
    #pragma unroll
    for (int i = 0; i < 8; ++i)
        #pragma unroll
        for (int j = 0; j < 4; ++j)
            acc[i][j] = (f32x4){0.f, 0.f, 0.f, 0.f};

    bf16x8 af[8], bf0, bf1;

// WAITE: vmcnt(8) at phase END (after MFMA, before trailing barrier).
#define PHASE(BUF, KK, NH, WAITE, STAGE_STMT) do {                                 \
    if ((NH) == 0) {                                                               \
        _Pragma("unroll")                                                          \
        for (int mi = 0; mi < 8; ++mi)                                             \
            af[mi] = LDA(BUF, KK, wr * 128 + mi * 16 + frow);                      \
    }                                                                              \
    bf0 = LDB(BUF, KK, wc * 64 + (NH) * 32 + frow);                                \
    bf1 = LDB(BUF, KK, wc * 64 + (NH) * 32 + 16 + frow);                           \
    STAGE_STMT;                                                                    \
    __builtin_amdgcn_s_barrier();                                                  \
    asm volatile("s_waitcnt lgkmcnt(0)" ::: "memory");                             \
    __builtin_amdgcn_s_setprio(1);                                                 \
    _Pragma("unroll")                                                              \
    for (int mi = 0; mi < 8; ++mi) {                                               \
        acc[mi][(NH)*2]   = __builtin_amdgcn_mfma_f32_16x16x32_bf16(               \
                                af[mi], bf0, acc[mi][(NH)*2], 0, 0, 0);            \
        acc[mi][(NH)*2+1] = __builtin_amdgcn_mfma_f32_16x16x32_bf16(               \
                                af[mi], bf1, acc[mi][(NH)*2+1], 0, 0, 0);          \
    }                                                                              \
    __builtin_amdgcn_s_setprio(0);                                                 \
    if (WAITE) asm volatile("s_waitcnt vmcnt(8)" ::: "memory");                    \
    __builtin_amdgcn_s_barrier();                                                  \
} while (0)

    // prologue: 6 STAGEs = 12 loads (tile0 full, tile1 kh0), then secure
    // S1/S2 (buf0 kh0) in EVERY wave before any wave reads: vmcnt(8)+barrier.
    STAGE(0, 0, 0, A,  m0, 0);  STAGE(0, 1, 0, Bm, n0, 0);
    STAGE(0, 0, 1, A,  m0, 0);  STAGE(0, 1, 1, Bm, n0, 0);
    STAGE(1, 0, 0, A,  m0, 1);  STAGE(1, 1, 0, Bm, n0, 1);
    asm volatile("s_waitcnt vmcnt(8)" ::: "memory");
    __builtin_amdgcn_s_barrier();

    for (int it = 0; it < NIT; ++it) {
        const int t1  = 2 * it + 1;
        const int tp2 = (2 * it + 2 < NT_K) ? 2 * it + 2 : NT_K - 1;
        const int tp3 = (2 * it + 3 < NT_K) ? 2 * it + 3 : NT_K - 1;
        PHASE(0, 0, 0, 0, STAGE(1, 0, 1, A,  m0, t1));   // P1
        PHASE(0, 0, 1, 1, STAGE(1, 1, 1, Bm, n0, t1));   // P2 end-wait -> buf0kh1 ready
        PHASE(0, 1, 0, 0, STAGE(0, 0, 0, A,  m0, tp2));  // P3
        PHASE(0, 1, 1, 1, STAGE(0, 1, 0, Bm, n0, tp2));  // P4 end-wait -> buf1kh0 ready
        PHASE(1, 0, 0, 0, STAGE(0, 0, 1, A,  m0, tp2));  // P5
        PHASE(1, 0, 1, 1, STAGE(0, 1, 1, Bm, n0, tp2));  // P6 end-wait -> buf1kh1 ready
        PHASE(1, 1, 0, 0, STAGE(1, 0, 0, A,  m0, tp3));  // P7
        PHASE(1, 1, 1, 1, STAGE(1, 1, 0, Bm, n0, tp3));  // P8 end-wait -> buf0kh0 ready
    }

    asm volatile("s_waitcnt vmcnt(0)" ::: "memory");   // drain tail prefetches

    // epilogue: C/D layout col = lane&15, row = (lane>>4)*4 + r
    const int crow = (lane >> 4) * 4;
    const int ccol = lane & 15;
    float bv4[4];
    #pragma unroll
    for (int ni = 0; ni < 4; ++ni)
        bv4[ni] = bias[n0 + wc * 64 + ni * 16 + ccol];
    #pragma unroll
    for (int mi = 0; mi < 8; ++mi) {
        #pragma unroll
        for (int r = 0; r < 4; ++r) {
            const size_t rowg = (size_t)(m0 + wr * 128 + mi * 16 + crow + r) * N;
            #pragma unroll
            for (int ni = 0; ni < 4; ++ni) {
                const int col = n0 + wc * 64 + ni * 16 + ccol;
                float v = acc[mi][ni][r] + bv4[ni];
                if constexpr (std::is_same<OutT, float>::value) {
                    C[rowg + col] = v;
                } else {
                    C[rowg + col] = f2b(v);
                }
            }
        }
    }
#undef PHASE
#undef LDA
#undef LDB
#undef STAGE
}

// ---------------- per-token head-mixing attention ----------------------
__global__ __launch_bounds__(256) void k_attn(
    const short* __restrict__ QKV, short* __restrict__ O)
{
    __shared__ short Ks[16][1032];
    __shared__ short Vs[16][1032];

    const int tid = threadIdx.x;
    const int tok0 = blockIdx.x * 16;

    for (int i = tid; i < 2048; i += 256) {
        int t = i >> 7;
        int j = i & 127;
        const size_t base = (size_t)(tok0 + t) * QKV_STRIDE;
        *reinterpret_cast<short8_t*>(&Ks[t][j * 8]) =
            *reinterpret_cast<const short8_t*>(&QKV[base + 1024 + j * 8]);
        *reinterpret_cast<short8_t*>(&Vs[t][j * 8]) =
            *reinterpret_cast<const short8_t*>(&QKV[base + 2048 + j * 8]);
    }
    __syncthreads();

    const int tl = tid >> 4;
    const int h  = tid & 15;

    float qf[64];
    const short* qp = QKV + (size_t)(tok0 + tl) * QKV_STRIDE + h * HD;
    #pragma unroll
    for (int i = 0; i < 8; ++i) {
        short8_t v = *reinterpret_cast<const short8_t*>(&qp[i * 8]);
        #pragma unroll
        for (int j = 0; j < 8; ++j) qf[i * 8 + j] = b2f(v[j]);
    }

    float s[16];
    #pragma unroll
    for (int g = 0; g < 16; ++g) {
        float a = 0.f;
        #pragma unroll
        for (int i = 0; i < 8; ++i) {
            short8_t kv = *reinterpret_cast<const short8_t*>(&Ks[tl][g * HD + i * 8]);
            #pragma unroll
            for (int j = 0; j < 8; ++j) a += qf[i * 8 + j] * b2f(kv[j]);
        }
        s[g] = a * 0.125f;
    }
    float mx = s[0];
    #pragma unroll
    for (int g = 1; g < 16; ++g) mx = fmaxf(mx, s[g]);
    float l = 0.f;
    #pragma unroll
    for (int g = 0; g < 16; ++g) { s[g] = __expf(s[g] - mx); l += s[g]; }
    const float inv = 1.f / l;
    #pragma unroll
    for (int g = 0; g < 16; ++g) s[g] *= inv;

    short* op = O + (size_t)(tok0 + tl) * E_DIM + h * HD;
    #pragma unroll
    for (int c = 0; c < 4; ++c) {
        float a[16];
        #pragma unroll
        for (int j = 0; j < 16; ++j) a[j] = 0.f;
        #pragma unroll
        for (int g = 0; g < 16; ++g) {
            short8_t v0 = *reinterpret_cast<const short8_t*>(&Vs[tl][g * HD + c * 16]);
            short8_t v1 = *reinterpret_cast<const short8_t*>(&Vs[tl][g * HD + c * 16 + 8]);
            #pragma unroll
            for (int j = 0; j < 8; ++j) {
                a[j]     += s[g] * b2f(v0[j]);
                a[8 + j] += s[g] * b2f(v1[j]);
            }
        }
        short8_t o0, o1;
        #pragma unroll
        for (int j = 0; j < 8; ++j) { o0[j] = f2b(a[j]); o1[j] = f2b(a[8 + j]); }
        *reinterpret_cast<short8_t*>(&op[c * 16])     = o0;
        *reinterpret_cast<short8_t*>(&op[c * 16 + 8]) = o1;
    }
}

extern "C" void kernel_launch(void* const* d_in, const int* in_sizes, int n_in,
                              void* d_out, int out_size, void* d_ws, size_t ws_size,
                              hipStream_t stream) {
    const float* x  = (const float*)d_in[0];
    const float* Wq = (const float*)d_in[1];
    const float* bq = (const float*)d_in[2];
    const float* Wk = (const float*)d_in[3];
    const float* bk = (const float*)d_in[4];
    const float* Wv = (const float*)d_in[5];
    const float* bv = (const float*)d_in[6];
    const float* Wo = (const float*)d_in[7];
    const float* bo = (const float*)d_in[8];
    float* out = (float*)d_out;

    const int T = in_sizes[0] / E_DIM;      // 32768 tokens
    char* ws = (char*)d_ws;
    const size_t SZ_X    = (size_t)T * E_DIM * 2;
    const size_t SZ_WQKV = (size_t)3 * E_DIM * E_DIM * 2;
    const size_t SZ_W    = (size_t)E_DIM * E_DIM * 2;
    const size_t SZ_B    = 3072 * sizeof(float) + 4096;

    short* xb    = (short*)(ws);
    short* Wqkvb = (short*)(ws + SZ_X);
    short* Wob   = (short*)(ws + SZ_X + SZ_WQKV);
    float* bqkv  = (float*)(ws + SZ_X + SZ_WQKV + SZ_W);
    short* QKVb  = (short*)(ws + SZ_X + SZ_WQKV + SZ_W + SZ_B);
    short* Ab    = xb;   // reuse x-bf16 buffer for attention output

    const int n4x = T * E_DIM / 4;
    const int n4w = E_DIM * E_DIM / 4;
    k_convert<<<dim3((n4x + 255) / 256), dim3(256), 0, stream>>>(x,  xb, n4x);
    k_convert<<<dim3((n4w + 255) / 256), dim3(256), 0, stream>>>(Wq, Wqkvb,                     n4w);
    k_convert<<<dim3((n4w + 255) / 256), dim3(256), 0, stream>>>(Wk, Wqkvb + E_DIM * E_DIM,     n4w);
    k_convert<<<dim3((n4w + 255) / 256), dim3(256), 0, stream>>>(Wv, Wqkvb + 2 * E_DIM * E_DIM, n4w);
    k_convert<<<dim3((n4w + 255) / 256), dim3(256), 0, stream>>>(Wo, Wob, n4w);
    k_bcat<<<dim3(12), dim3(256), 0, stream>>>(bq, bk, bv, bqkv);

    // fused QKV GEMM: [T][3072]
    k_gemm256<short><<<dim3((T / 256) * (QKV_STRIDE / 256)), dim3(512), 0, stream>>>(
        xb, Wqkvb, bqkv, QKVb, QKV_STRIDE / 256, QKV_STRIDE);

    k_attn<<<dim3(T / 16), dim3(256), 0, stream>>>(QKVb, Ab);

    // output GEMM: [T][1024] fp32
    k_gemm256<float><<<dim3((T / 256) * (E_DIM / 256)), dim3(512), 0, stream>>>(
        Ab, Wob, bo, out, E_DIM / 256, E_DIM);
}